// Round 18
// baseline (270.028 us; speedup 1.0000x reference)
//
#include <hip/hip_runtime.h>
#include <hip/hip_fp16.h>
#include <math.h>

#define NEG_SLOPE 0.2f
#define CAP 64   // slots per dst; deg ~ Poisson(17), P(deg>64) ~ e^-41 per node

static __device__ __forceinline__ void atomAdd(float* a, float v) {
    unsafeAtomicAdd(a, v);
}

// Edge-layout probe: int64 indices (<2^31) have all-zero odd 32-bit words.
static __device__ __forceinline__ bool edges_are_i64(const int* __restrict__ ei) {
    return (ei[1] | ei[3] | ei[5] | ei[7]) == 0;
}
static __device__ __forceinline__ int ldsrc(const int* __restrict__ ei, int e, int E, bool i64) {
    return i64 ? ei[2 * e] : ei[e];
}
static __device__ __forceinline__ int lddst(const int* __restrict__ ei, int e, int E, bool i64) {
    return i64 ? ei[2 * (E + e)] : ei[E + e];
}

// ==== fuseA: role-split blocks — scatter || gemm1 (independent work) ====
// NOTE: plain launch only. R17: hipLaunchCooperativeKernel breaks graph capture.
__global__ __launch_bounds__(256, 4) void fuseA_k(const int* __restrict__ ei,
                                                  int* __restrict__ deg,
                                                  int* __restrict__ col,
                                                  const float* __restrict__ x,
                                                  const float* __restrict__ W1,
                                                  const float* __restrict__ aws,
                                                  const float* __restrict__ awd,
                                                  __half* __restrict__ h,
                                                  float* __restrict__ as_,
                                                  float* __restrict__ ad_,
                                                  int E, int N) {
    __shared__ float smem[10240];          // 40 KB: Ws 8192 + xs 2048
    const int tid = threadIdx.x;
    const int nScat = gridDim.x >> 1;

    if (blockIdx.x < nScat) {
        // ---- scatter role: slot-CSR build ----
        const bool i64 = edges_are_i64(ei);
        const int ET = E + N;
        for (int e = blockIdx.x * 256 + tid; e < ET; e += nScat * 256) {
            int s, d;
            if (e < E) { s = ldsrc(ei, e, E, i64); d = lddst(ei, e, E, i64); }
            else       { s = d = e - E; }
            int pos = atomicAdd(&deg[d], 1);
            if (pos < CAP) col[d * CAP + pos] = s;
        }
        return;
    }

    // ---- gemm1 role (persistent 32-row tiles, 4x4 reg tile, fused logits) ----
    float* Ws = smem;                      // [k][j] 64x128
    float* xs = smem + 8192;               // [row][k] 32x64
    const int cgi = tid & 31, rg = tid >> 5;
    const int nG = gridDim.x - nScat;
    const int tiles = (N + 31) / 32;
#pragma unroll 1
    for (int i = tid; i < 8192; i += 256) Ws[i] = W1[i];

    const int jbase = cgi * 4;
    const int head = cgi >> 3;
    const float a0 = aws[jbase], a1 = aws[jbase + 1], a2 = aws[jbase + 2], a3 = aws[jbase + 3];
    const float d0 = awd[jbase], d1 = awd[jbase + 1], d2 = awd[jbase + 2], d3 = awd[jbase + 3];

#pragma unroll 1
    for (int t = blockIdx.x - nScat; t < tiles; t += nG) {
        const int r0 = t * 32;
        __syncthreads();                   // covers Ws fill + previous tile reads
        {
            const float* src = x + (size_t)r0 * 64;
            const int limit = (N - r0) * 64;
#pragma unroll 1
            for (int i = tid * 4; i < 2048; i += 1024) {
                float4 v = (i < limit) ? *(const float4*)(src + i) : make_float4(0, 0, 0, 0);
                *(float4*)(xs + i) = v;
            }
        }
        __syncthreads();

        float acc[4][4] = {};
#pragma unroll 2
        for (int k = 0; k < 64; k += 4) {
            float4 w0 = *(const float4*)(Ws + (k + 0) * 128 + cgi * 4);
            float4 w1 = *(const float4*)(Ws + (k + 1) * 128 + cgi * 4);
            float4 w2 = *(const float4*)(Ws + (k + 2) * 128 + cgi * 4);
            float4 w3 = *(const float4*)(Ws + (k + 3) * 128 + cgi * 4);
            float4 xv[4];
#pragma unroll
            for (int q = 0; q < 4; ++q) xv[q] = *(const float4*)(xs + (rg * 4 + q) * 64 + k);
#pragma unroll
            for (int q = 0; q < 4; ++q) {
                float4 xq = xv[q];
                acc[q][0] += xq.x * w0.x + xq.y * w1.x + xq.z * w2.x + xq.w * w3.x;
                acc[q][1] += xq.x * w0.y + xq.y * w1.y + xq.z * w2.y + xq.w * w3.y;
                acc[q][2] += xq.x * w0.z + xq.y * w1.z + xq.z * w2.z + xq.w * w3.z;
                acc[q][3] += xq.x * w0.w + xq.y * w1.w + xq.z * w2.w + xq.w * w3.w;
            }
        }

        float ps[4], pd[4];
#pragma unroll
        for (int q = 0; q < 4; ++q) {
            ps[q] = acc[q][0] * a0 + acc[q][1] * a1 + acc[q][2] * a2 + acc[q][3] * a3;
            pd[q] = acc[q][0] * d0 + acc[q][1] * d1 + acc[q][2] * d2 + acc[q][3] * d3;
            int row = r0 + rg * 4 + q;
            if (row < N) {
                __half hv[4];
                hv[0] = __float2half(acc[q][0]); hv[1] = __float2half(acc[q][1]);
                hv[2] = __float2half(acc[q][2]); hv[3] = __float2half(acc[q][3]);
                *(uint2*)(h + (size_t)row * 128 + jbase) = *(uint2*)hv;
            }
        }
#pragma unroll
        for (int off = 4; off; off >>= 1) {
#pragma unroll
            for (int q = 0; q < 4; ++q) {
                ps[q] += __shfl_down(ps[q], off, 8);
                pd[q] += __shfl_down(pd[q], off, 8);
            }
        }
        if ((cgi & 7) == 0) {
#pragma unroll
            for (int q = 0; q < 4; ++q) {
                int row = r0 + rg * 4 + q;
                if (row < N) { as_[row * 4 + head] = ps[q]; ad_[row * 4 + head] = pd[q]; }
            }
        }
    }
}

// ---- gemm2: 4x4 register tile, 128-row blocks, k split 2x64, fp16 out ----
__global__ __launch_bounds__(256, 4) void gemm2_k(const float* __restrict__ hact,
                                                  const float* __restrict__ W,
                                                  const float* __restrict__ aws,
                                                  const float* __restrict__ awd,
                                                  __half* __restrict__ h2,
                                                  float* __restrict__ as_,
                                                  float* __restrict__ ad_, int N) {
    __shared__ float Ws[128 * 32];     // 16 KB, [k][j]
    __shared__ float xs[128 * 68];     // 34 KB, [row][k], stride 68
    const int tid = threadIdx.x;
    const int cg = tid & 7, rg = tid >> 3;
    const int r0 = blockIdx.x * 128;
    for (int i = tid; i < 4096; i += 256) Ws[i] = W[i];

    float acc[4][4] = {};
#pragma unroll 1
    for (int p = 0; p < 2; ++p) {
        __syncthreads();
#pragma unroll 2
        for (int i = tid * 4; i < 8192; i += 1024) {
            int row = i >> 6, kk = i & 63;
            float4 v = (r0 + row < N)
                ? *(const float4*)(hact + (size_t)(r0 + row) * 128 + p * 64 + kk)
                : make_float4(0, 0, 0, 0);
            *(float4*)(xs + row * 68 + kk) = v;
        }
        __syncthreads();
#pragma unroll 2
        for (int k = 0; k < 64; k += 4) {
            float4 w0 = *(const float4*)(Ws + (p * 64 + k + 0) * 32 + cg * 4);
            float4 w1 = *(const float4*)(Ws + (p * 64 + k + 1) * 32 + cg * 4);
            float4 w2 = *(const float4*)(Ws + (p * 64 + k + 2) * 32 + cg * 4);
            float4 w3 = *(const float4*)(Ws + (p * 64 + k + 3) * 32 + cg * 4);
            float4 xv[4];
#pragma unroll
            for (int q = 0; q < 4; ++q) xv[q] = *(const float4*)(xs + (rg * 4 + q) * 68 + k);
#pragma unroll
            for (int q = 0; q < 4; ++q) {
                float4 xq = xv[q];
                acc[q][0] += xq.x * w0.x + xq.y * w1.x + xq.z * w2.x + xq.w * w3.x;
                acc[q][1] += xq.x * w0.y + xq.y * w1.y + xq.z * w2.y + xq.w * w3.y;
                acc[q][2] += xq.x * w0.z + xq.y * w1.z + xq.z * w2.z + xq.w * w3.z;
                acc[q][3] += xq.x * w0.w + xq.y * w1.w + xq.z * w2.w + xq.w * w3.w;
            }
        }
    }

    const int jbase = cg * 4;
    const float a0 = aws[jbase], a1 = aws[jbase + 1], a2 = aws[jbase + 2], a3 = aws[jbase + 3];
    const float d0 = awd[jbase], d1 = awd[jbase + 1], d2 = awd[jbase + 2], d3 = awd[jbase + 3];
    float ps[4], pd[4];
#pragma unroll
    for (int q = 0; q < 4; ++q) {
        ps[q] = acc[q][0] * a0 + acc[q][1] * a1 + acc[q][2] * a2 + acc[q][3] * a3;
        pd[q] = acc[q][0] * d0 + acc[q][1] * d1 + acc[q][2] * d2 + acc[q][3] * d3;
        int row = r0 + rg * 4 + q;
        if (row < N) {
            __half hv[4];
            hv[0] = __float2half(acc[q][0]); hv[1] = __float2half(acc[q][1]);
            hv[2] = __float2half(acc[q][2]); hv[3] = __float2half(acc[q][3]);
            *(uint2*)(h2 + (size_t)row * 32 + jbase) = *(uint2*)hv;
        }
    }
#pragma unroll
    for (int off = 4; off; off >>= 1) {
#pragma unroll
        for (int q = 0; q < 4; ++q) {
            ps[q] += __shfl_down(ps[q], off, 8);
            pd[q] += __shfl_down(pd[q], off, 8);
        }
    }
    if (cg == 0) {
#pragma unroll
        for (int q = 0; q < 4; ++q) {
            int row = r0 + rg * 4 + q;
            if (row < N) { as_[row] = ps[q]; ad_[row] = pd[q]; }
        }
    }
}

// ---- pull aggregation L1: slot-CSR, unroll-8 fp16 gathers, fused bias/ELU ----
__global__ __launch_bounds__(256) void pull_agg1_k(const int* __restrict__ deg,
                                                   const int* __restrict__ col,
                                                   const float* __restrict__ asrc,
                                                   const float* __restrict__ adst,
                                                   const __half* __restrict__ h,
                                                   const float* __restrict__ b1,
                                                   float* __restrict__ hact, int N) {
    int wave = (blockIdx.x * 256 + threadIdx.x) >> 6;
    int lane = threadIdx.x & 63;
    if (wave >= N) return;
    const int d = wave;
    const int hd = lane >> 4;
    const float ad = adst[d * 4 + hd];
    const int* cl = col + d * CAP;
    int cnt = deg[d]; if (cnt > CAP) cnt = CAP;
    float acc0 = 0.0f, acc1 = 0.0f, den = 0.0f;
    int i = 0;
    for (; i + 8 <= cnt; i += 8) {
        int s[8]; float v[8]; __half2 g[8];
#pragma unroll
        for (int u = 0; u < 8; ++u) s[u] = cl[i + u];
#pragma unroll
        for (int u = 0; u < 8; ++u) v[u] = asrc[s[u] * 4 + hd] + ad;
#pragma unroll
        for (int u = 0; u < 8; ++u) g[u] = *(const __half2*)(h + (size_t)s[u] * 128 + lane * 2);
#pragma unroll
        for (int u = 0; u < 8; ++u) {
            float vv = v[u] > 0.0f ? v[u] : NEG_SLOPE * v[u];
            float p = __expf(vv);
            float2 gf = __half22float2(g[u]);
            den += p; acc0 += p * gf.x; acc1 += p * gf.y;
        }
    }
    for (; i < cnt; ++i) {
        int s = cl[i];
        float v = asrc[s * 4 + hd] + ad;
        v = v > 0.0f ? v : NEG_SLOPE * v;
        float p = __expf(v);
        float2 gf = __half22float2(*(const __half2*)(h + (size_t)s * 128 + lane * 2));
        den += p; acc0 += p * gf.x; acc1 += p * gf.y;
    }
    float inv = 1.0f / den;                      // den>0: self-loop guaranteed
    float o0 = acc0 * inv + b1[lane * 2];
    float o1 = acc1 * inv + b1[lane * 2 + 1];
    o0 = o0 > 0.0f ? o0 : expm1f(o0);
    o1 = o1 > 0.0f ? o1 : expm1f(o1);
    *(float2*)(hact + (size_t)d * 128 + lane * 2) = make_float2(o0, o1);
}

// ---- pull aggregation L2 (H=1,C=32): 32-lane group per dst, fp16 gathers ----
__global__ __launch_bounds__(256) void pull_agg2_k(const int* __restrict__ deg,
                                                   const int* __restrict__ col,
                                                   const float* __restrict__ asrc,
                                                   const float* __restrict__ adst,
                                                   const __half* __restrict__ h,
                                                   float* __restrict__ out, int N) {
    int grp = (blockIdx.x * 256 + threadIdx.x) >> 5;
    int lane = threadIdx.x & 31;
    if (grp >= N) return;
    const int d = grp;
    const float ad = adst[d];
    const int* cl = col + d * CAP;
    int cnt = deg[d]; if (cnt > CAP) cnt = CAP;
    float acc = 0.0f, den = 0.0f;
    int i = 0;
    for (; i + 8 <= cnt; i += 8) {
        int s[8]; float v[8]; __half g[8];
#pragma unroll
        for (int u = 0; u < 8; ++u) s[u] = cl[i + u];
#pragma unroll
        for (int u = 0; u < 8; ++u) v[u] = asrc[s[u]] + ad;
#pragma unroll
        for (int u = 0; u < 8; ++u) g[u] = h[(size_t)s[u] * 32 + lane];
#pragma unroll
        for (int u = 0; u < 8; ++u) {
            float vv = v[u] > 0.0f ? v[u] : NEG_SLOPE * v[u];
            float p = __expf(vv);
            den += p; acc += p * __half2float(g[u]);
        }
    }
    for (; i < cnt; ++i) {
        int s = cl[i];
        float v = asrc[s] + ad;
        v = v > 0.0f ? v : NEG_SLOPE * v;
        float p = __expf(v);
        den += p; acc += p * __half2float(h[(size_t)s * 32 + lane]);
    }
    out[(size_t)d * 32 + lane] = acc / den;
}

__global__ __launch_bounds__(256) void colmean_k(const float* __restrict__ out2,
                                                 float* __restrict__ gsum, int N) {
    __shared__ float lds[256];
    int tid = threadIdx.x;
    int c = tid % 32;
    int rg = tid / 32;
    float acc = 0.0f;
    for (int r = blockIdx.x * 8 + rg; r < N; r += gridDim.x * 8)
        acc += out2[(size_t)r * 32 + c];
    lds[tid] = acc;
    __syncthreads();
    if (tid < 32) {
        float s = 0.0f;
#pragma unroll
        for (int g = 0; g < 8; ++g) s += lds[g * 32 + tid];
        atomAdd(&gsum[tid], s);
    }
}

__global__ void final_k(const float* __restrict__ gsum, const float* __restrict__ b2w,
                        const float* __restrict__ linW, const float* __restrict__ linb,
                        float* __restrict__ out, int N) {
    if (threadIdx.x != 0 || blockIdx.x != 0) return;
    float g[32];
#pragma unroll
    for (int c = 0; c < 32; ++c) g[c] = gsum[c] / (float)N + b2w[c];
    float lo[3];
#pragma unroll
    for (int j = 0; j < 3; ++j) {
        float acc = linb[j];
#pragma unroll
        for (int c = 0; c < 32; ++c) acc += g[c] * linW[c * 3 + j];
        lo[j] = acc;
    }
    float mx = fmaxf(lo[0], fmaxf(lo[1], lo[2]));
    float ex[3], se = 0.0f;
#pragma unroll
    for (int j = 0; j < 3; ++j) { ex[j] = __expf(lo[j] - mx); se += ex[j]; }
#pragma unroll
    for (int j = 0; j < 3; ++j) out[j] = ex[j] / se;
}

extern "C" void kernel_launch(void* const* d_in, const int* in_sizes, int n_in,
                              void* d_out, int out_size, void* d_ws, size_t ws_size,
                              hipStream_t stream) {
    const float* x    = (const float*)d_in[0];
    const float* W1   = (const float*)d_in[1];
    const float* as1w = (const float*)d_in[2];
    const float* ad1w = (const float*)d_in[3];
    const float* b1   = (const float*)d_in[4];
    const float* W2   = (const float*)d_in[5];
    const float* as2w = (const float*)d_in[6];
    const float* ad2w = (const float*)d_in[7];
    const float* b2w  = (const float*)d_in[8];
    const float* linW = (const float*)d_in[9];
    const float* linb = (const float*)d_in[10];
    const int*   ei   = (const int*)d_in[11];

    const int N = in_sizes[0] / 64;       // 50000
    const int E = in_sizes[11] / 2;       // 800000

    float* ws = (float*)d_ws;
    __half* h1h  = (__half*)ws;                          // N*128 halves
    float*  hact = ws + (size_t)N * 64;                  // N*128 fp32
    float* asrc1 = hact + (size_t)N * 128;               // N*4
    float* adst1 = asrc1 + (size_t)N * 4;                // N*4
    float* asrc2 = adst1 + (size_t)N * 4;                // N
    float* adst2 = asrc2 + (size_t)N;                    // N
    float* gsum  = adst2 + (size_t)N;                    // 32
    // layer-2 aliases inside h1h region (dead after pull_agg1):
    __half* h2h  = (__half*)ws;                          // N*32 halves
    float*  out2 = ws + (size_t)N * 16;                  // N*32 fp32
    // int region: deg + slot-col
    int* deg     = (int*)(gsum + 32);        // N
    int* col     = deg + N;                  // N*CAP

    auto cdiv = [](int a, int b) { return (a + b - 1) / b; };

    hipMemsetAsync(deg, 0, (size_t)N * sizeof(int), stream);
    hipMemsetAsync(gsum, 0, 32 * sizeof(float), stream);

    // ---- A: scatter || gemm1 (role-split, plain launch) ----
    fuseA_k<<<2048, 256, 0, stream>>>(ei, deg, col, x, W1, as1w, ad1w,
                                      h1h, asrc1, adst1, E, N);

    // ---- layer 1 aggregation ----
    pull_agg1_k<<<cdiv(N, 4), 256, 0, stream>>>(deg, col, asrc1, adst1, h1h, b1, hact, N);

    // ---- layer 2 ----
    gemm2_k<<<cdiv(N, 128), 256, 0, stream>>>(hact, W2, as2w, ad2w, h2h, asrc2, adst2, N);
    pull_agg2_k<<<cdiv(N, 8), 256, 0, stream>>>(deg, col, asrc2, adst2, h2h, out2, N);

    // ---- readout ----
    colmean_k<<<256, 256, 0, stream>>>(out2, gsum, N);
    final_k<<<1, 64, 0, stream>>>(gsum, b2w, linW, linb, (float*)d_out, N);
}

// Round 19
// 247.012 us; speedup vs baseline: 1.0932x; 1.0932x over previous
//
#include <hip/hip_runtime.h>
#include <hip/hip_fp16.h>
#include <math.h>

#define NEG_SLOPE 0.2f
#define CAP 64    // slots per dst; deg ~ Poisson(17), P(deg>64) ~ e^-41 per node
#define SCB 2048  // scatter blocks: 8 XCD slice-groups x 256 blocks

static __device__ __forceinline__ void atomAdd(float* a, float v) {
    unsafeAtomicAdd(a, v);
}

// Edge-layout probe: int64 indices (<2^31) have all-zero odd 32-bit words.
static __device__ __forceinline__ bool edges_are_i64(const int* __restrict__ ei) {
    return (ei[1] | ei[3] | ei[5] | ei[7]) == 0;
}
static __device__ __forceinline__ int ldsrc(const int* __restrict__ ei, int e, int E, bool i64) {
    return i64 ? ei[2 * e] : ei[e];
}
static __device__ __forceinline__ int lddst(const int* __restrict__ ei, int e, int E, bool i64) {
    return i64 ? ei[2 * (E + e)] : ei[E + e];
}

// ---- XCD-sliced slot-CSR scatter ----
// Group g = blockIdx&7 (round-robin XCD heuristic; correctness independent of
// the physical mapping) scans ALL edges, writes only dsts in its N/8 slice.
// Each XCD's col slice (1.6 MB) fits its private L2 -> slot writes coalesce
// in-cache instead of 16x-amplified random-line memory writes (R18: 48.7 MB).
__global__ __launch_bounds__(256) void scatter_k(const int* __restrict__ ei,
                                                 int* __restrict__ deg,
                                                 int* __restrict__ col, int E, int N) {
    const int tid = threadIdx.x;
    const int grp = blockIdx.x & 7;
    const int bin = blockIdx.x >> 3;
    const int nb  = gridDim.x >> 3;
    const bool i64 = edges_are_i64(ei);
    const int ET = E + N;
    const int d0 = (int)((long long)grp * N / 8);
    const int d1 = (int)((long long)(grp + 1) * N / 8);
    for (int e = bin * 256 + tid; e < ET; e += nb * 256) {
        int s, d;
        if (e < E) { s = ldsrc(ei, e, E, i64); d = lddst(ei, e, E, i64); }
        else       { s = d = e - E; }
        if (d >= d0 && d < d1) {
            int pos = atomicAdd(&deg[d], 1);
            if (pos < CAP) col[d * CAP + pos] = s;
        }
    }
}

// ---- gemm1: 4x4 register tile, 32-row blocks, fused att logits, fp16 out ----
__global__ __launch_bounds__(256, 4) void gemm1_k(const float* __restrict__ x,
                                                  const float* __restrict__ W,
                                                  const float* __restrict__ aws,
                                                  const float* __restrict__ awd,
                                                  __half* __restrict__ h,
                                                  float* __restrict__ as_,
                                                  float* __restrict__ ad_, int N) {
    __shared__ float Ws[64 * 128];   // 32 KB, [k][j]
    __shared__ float xs[32 * 64];    // 8 KB, [row][k]
    const int tid = threadIdx.x;
    const int cg = tid & 31, rg = tid >> 5;
    const int r0 = blockIdx.x * 32;
#pragma unroll 1
    for (int i = tid; i < 8192; i += 256) Ws[i] = W[i];
    {
        const float* src = x + (size_t)r0 * 64;
        const int limit = (N - r0) * 64;
#pragma unroll 1
        for (int i = tid * 4; i < 2048; i += 1024) {
            float4 v = (i < limit) ? *(const float4*)(src + i) : make_float4(0, 0, 0, 0);
            *(float4*)(xs + i) = v;
        }
    }
    __syncthreads();

    float acc[4][4] = {};
#pragma unroll 2
    for (int k = 0; k < 64; k += 4) {
        float4 w0 = *(const float4*)(Ws + (k + 0) * 128 + cg * 4);
        float4 w1 = *(const float4*)(Ws + (k + 1) * 128 + cg * 4);
        float4 w2 = *(const float4*)(Ws + (k + 2) * 128 + cg * 4);
        float4 w3 = *(const float4*)(Ws + (k + 3) * 128 + cg * 4);
        float4 xv[4];
#pragma unroll
        for (int q = 0; q < 4; ++q) xv[q] = *(const float4*)(xs + (rg * 4 + q) * 64 + k);
#pragma unroll
        for (int q = 0; q < 4; ++q) {
            float4 xq = xv[q];
            acc[q][0] += xq.x * w0.x + xq.y * w1.x + xq.z * w2.x + xq.w * w3.x;
            acc[q][1] += xq.x * w0.y + xq.y * w1.y + xq.z * w2.y + xq.w * w3.y;
            acc[q][2] += xq.x * w0.z + xq.y * w1.z + xq.z * w2.z + xq.w * w3.z;
            acc[q][3] += xq.x * w0.w + xq.y * w1.w + xq.z * w2.w + xq.w * w3.w;
        }
    }

    const int jbase = cg * 4;
    const int head = cg >> 3;
    const float a0 = aws[jbase], a1 = aws[jbase + 1], a2 = aws[jbase + 2], a3 = aws[jbase + 3];
    const float d0 = awd[jbase], d1 = awd[jbase + 1], d2 = awd[jbase + 2], d3 = awd[jbase + 3];
    float ps[4], pd[4];
#pragma unroll
    for (int q = 0; q < 4; ++q) {
        ps[q] = acc[q][0] * a0 + acc[q][1] * a1 + acc[q][2] * a2 + acc[q][3] * a3;
        pd[q] = acc[q][0] * d0 + acc[q][1] * d1 + acc[q][2] * d2 + acc[q][3] * d3;
        int row = r0 + rg * 4 + q;
        if (row < N) {
            __half hv[4];
            hv[0] = __float2half(acc[q][0]); hv[1] = __float2half(acc[q][1]);
            hv[2] = __float2half(acc[q][2]); hv[3] = __float2half(acc[q][3]);
            *(uint2*)(h + (size_t)row * 128 + jbase) = *(uint2*)hv;
        }
    }
#pragma unroll
    for (int off = 4; off; off >>= 1) {
#pragma unroll
        for (int q = 0; q < 4; ++q) {
            ps[q] += __shfl_down(ps[q], off, 8);
            pd[q] += __shfl_down(pd[q], off, 8);
        }
    }
    if ((cg & 7) == 0) {
#pragma unroll
        for (int q = 0; q < 4; ++q) {
            int row = r0 + rg * 4 + q;
            if (row < N) { as_[row * 4 + head] = ps[q]; ad_[row * 4 + head] = pd[q]; }
        }
    }
}

// ---- gemm2: 4x4 register tile, 128-row blocks, k split 2x64, fp16 out ----
__global__ __launch_bounds__(256, 4) void gemm2_k(const float* __restrict__ hact,
                                                  const float* __restrict__ W,
                                                  const float* __restrict__ aws,
                                                  const float* __restrict__ awd,
                                                  __half* __restrict__ h2,
                                                  float* __restrict__ as_,
                                                  float* __restrict__ ad_, int N) {
    __shared__ float Ws[128 * 32];     // 16 KB, [k][j]
    __shared__ float xs[128 * 68];     // 34 KB, [row][k], stride 68
    const int tid = threadIdx.x;
    const int cg = tid & 7, rg = tid >> 3;
    const int r0 = blockIdx.x * 128;
    for (int i = tid; i < 4096; i += 256) Ws[i] = W[i];

    float acc[4][4] = {};
#pragma unroll 1
    for (int p = 0; p < 2; ++p) {
        __syncthreads();
#pragma unroll 2
        for (int i = tid * 4; i < 8192; i += 1024) {
            int row = i >> 6, kk = i & 63;
            float4 v = (r0 + row < N)
                ? *(const float4*)(hact + (size_t)(r0 + row) * 128 + p * 64 + kk)
                : make_float4(0, 0, 0, 0);
            *(float4*)(xs + row * 68 + kk) = v;
        }
        __syncthreads();
#pragma unroll 2
        for (int k = 0; k < 64; k += 4) {
            float4 w0 = *(const float4*)(Ws + (p * 64 + k + 0) * 32 + cg * 4);
            float4 w1 = *(const float4*)(Ws + (p * 64 + k + 1) * 32 + cg * 4);
            float4 w2 = *(const float4*)(Ws + (p * 64 + k + 2) * 32 + cg * 4);
            float4 w3 = *(const float4*)(Ws + (p * 64 + k + 3) * 32 + cg * 4);
            float4 xv[4];
#pragma unroll
            for (int q = 0; q < 4; ++q) xv[q] = *(const float4*)(xs + (rg * 4 + q) * 68 + k);
#pragma unroll
            for (int q = 0; q < 4; ++q) {
                float4 xq = xv[q];
                acc[q][0] += xq.x * w0.x + xq.y * w1.x + xq.z * w2.x + xq.w * w3.x;
                acc[q][1] += xq.x * w0.y + xq.y * w1.y + xq.z * w2.y + xq.w * w3.y;
                acc[q][2] += xq.x * w0.z + xq.y * w1.z + xq.z * w2.z + xq.w * w3.z;
                acc[q][3] += xq.x * w0.w + xq.y * w1.w + xq.z * w2.w + xq.w * w3.w;
            }
        }
    }

    const int jbase = cg * 4;
    const float a0 = aws[jbase], a1 = aws[jbase + 1], a2 = aws[jbase + 2], a3 = aws[jbase + 3];
    const float d0 = awd[jbase], d1 = awd[jbase + 1], d2 = awd[jbase + 2], d3 = awd[jbase + 3];
    float ps[4], pd[4];
#pragma unroll
    for (int q = 0; q < 4; ++q) {
        ps[q] = acc[q][0] * a0 + acc[q][1] * a1 + acc[q][2] * a2 + acc[q][3] * a3;
        pd[q] = acc[q][0] * d0 + acc[q][1] * d1 + acc[q][2] * d2 + acc[q][3] * d3;
        int row = r0 + rg * 4 + q;
        if (row < N) {
            __half hv[4];
            hv[0] = __float2half(acc[q][0]); hv[1] = __float2half(acc[q][1]);
            hv[2] = __float2half(acc[q][2]); hv[3] = __float2half(acc[q][3]);
            *(uint2*)(h2 + (size_t)row * 32 + jbase) = *(uint2*)hv;
        }
    }
#pragma unroll
    for (int off = 4; off; off >>= 1) {
#pragma unroll
        for (int q = 0; q < 4; ++q) {
            ps[q] += __shfl_down(ps[q], off, 8);
            pd[q] += __shfl_down(pd[q], off, 8);
        }
    }
    if (cg == 0) {
#pragma unroll
        for (int q = 0; q < 4; ++q) {
            int row = r0 + rg * 4 + q;
            if (row < N) { as_[row] = ps[q]; ad_[row] = pd[q]; }
        }
    }
}

// ---- pull aggregation L1: slot-CSR, unroll-8 fp16 gathers, fused bias/ELU ----
__global__ __launch_bounds__(256) void pull_agg1_k(const int* __restrict__ deg,
                                                   const int* __restrict__ col,
                                                   const float* __restrict__ asrc,
                                                   const float* __restrict__ adst,
                                                   const __half* __restrict__ h,
                                                   const float* __restrict__ b1,
                                                   float* __restrict__ hact, int N) {
    int wave = (blockIdx.x * 256 + threadIdx.x) >> 6;
    int lane = threadIdx.x & 63;
    if (wave >= N) return;
    const int d = wave;
    const int hd = lane >> 4;
    const float ad = adst[d * 4 + hd];
    const int* cl = col + d * CAP;
    int cnt = deg[d]; if (cnt > CAP) cnt = CAP;
    float acc0 = 0.0f, acc1 = 0.0f, den = 0.0f;
    int i = 0;
    for (; i + 8 <= cnt; i += 8) {
        int s[8]; float v[8]; __half2 g[8];
#pragma unroll
        for (int u = 0; u < 8; ++u) s[u] = cl[i + u];
#pragma unroll
        for (int u = 0; u < 8; ++u) v[u] = asrc[s[u] * 4 + hd] + ad;
#pragma unroll
        for (int u = 0; u < 8; ++u) g[u] = *(const __half2*)(h + (size_t)s[u] * 128 + lane * 2);
#pragma unroll
        for (int u = 0; u < 8; ++u) {
            float vv = v[u] > 0.0f ? v[u] : NEG_SLOPE * v[u];
            float p = __expf(vv);
            float2 gf = __half22float2(g[u]);
            den += p; acc0 += p * gf.x; acc1 += p * gf.y;
        }
    }
    for (; i < cnt; ++i) {
        int s = cl[i];
        float v = asrc[s * 4 + hd] + ad;
        v = v > 0.0f ? v : NEG_SLOPE * v;
        float p = __expf(v);
        float2 gf = __half22float2(*(const __half2*)(h + (size_t)s * 128 + lane * 2));
        den += p; acc0 += p * gf.x; acc1 += p * gf.y;
    }
    float inv = 1.0f / den;                      // den>0: self-loop guaranteed
    float o0 = acc0 * inv + b1[lane * 2];
    float o1 = acc1 * inv + b1[lane * 2 + 1];
    o0 = o0 > 0.0f ? o0 : expm1f(o0);
    o1 = o1 > 0.0f ? o1 : expm1f(o1);
    *(float2*)(hact + (size_t)d * 128 + lane * 2) = make_float2(o0, o1);
}

// ---- pull aggregation L2 (H=1,C=32): 32-lane group per dst, fp16 gathers ----
__global__ __launch_bounds__(256) void pull_agg2_k(const int* __restrict__ deg,
                                                   const int* __restrict__ col,
                                                   const float* __restrict__ asrc,
                                                   const float* __restrict__ adst,
                                                   const __half* __restrict__ h,
                                                   float* __restrict__ out, int N) {
    int grp = (blockIdx.x * 256 + threadIdx.x) >> 5;
    int lane = threadIdx.x & 31;
    if (grp >= N) return;
    const int d = grp;
    const float ad = adst[d];
    const int* cl = col + d * CAP;
    int cnt = deg[d]; if (cnt > CAP) cnt = CAP;
    float acc = 0.0f, den = 0.0f;
    int i = 0;
    for (; i + 8 <= cnt; i += 8) {
        int s[8]; float v[8]; __half g[8];
#pragma unroll
        for (int u = 0; u < 8; ++u) s[u] = cl[i + u];
#pragma unroll
        for (int u = 0; u < 8; ++u) v[u] = asrc[s[u]] + ad;
#pragma unroll
        for (int u = 0; u < 8; ++u) g[u] = h[(size_t)s[u] * 32 + lane];
#pragma unroll
        for (int u = 0; u < 8; ++u) {
            float vv = v[u] > 0.0f ? v[u] : NEG_SLOPE * v[u];
            float p = __expf(vv);
            den += p; acc += p * __half2float(g[u]);
        }
    }
    for (; i < cnt; ++i) {
        int s = cl[i];
        float v = asrc[s] + ad;
        v = v > 0.0f ? v : NEG_SLOPE * v;
        float p = __expf(v);
        den += p; acc += p * __half2float(h[(size_t)s * 32 + lane]);
    }
    out[(size_t)d * 32 + lane] = acc / den;
}

__global__ __launch_bounds__(256) void colmean_k(const float* __restrict__ out2,
                                                 float* __restrict__ gsum, int N) {
    __shared__ float lds[256];
    int tid = threadIdx.x;
    int c = tid % 32;
    int rg = tid / 32;
    float acc = 0.0f;
    for (int r = blockIdx.x * 8 + rg; r < N; r += gridDim.x * 8)
        acc += out2[(size_t)r * 32 + c];
    lds[tid] = acc;
    __syncthreads();
    if (tid < 32) {
        float s = 0.0f;
#pragma unroll
        for (int g = 0; g < 8; ++g) s += lds[g * 32 + tid];
        atomAdd(&gsum[tid], s);
    }
}

__global__ void final_k(const float* __restrict__ gsum, const float* __restrict__ b2w,
                        const float* __restrict__ linW, const float* __restrict__ linb,
                        float* __restrict__ out, int N) {
    if (threadIdx.x != 0 || blockIdx.x != 0) return;
    float g[32];
#pragma unroll
    for (int c = 0; c < 32; ++c) g[c] = gsum[c] / (float)N + b2w[c];
    float lo[3];
#pragma unroll
    for (int j = 0; j < 3; ++j) {
        float acc = linb[j];
#pragma unroll
        for (int c = 0; c < 32; ++c) acc += g[c] * linW[c * 3 + j];
        lo[j] = acc;
    }
    float mx = fmaxf(lo[0], fmaxf(lo[1], lo[2]));
    float ex[3], se = 0.0f;
#pragma unroll
    for (int j = 0; j < 3; ++j) { ex[j] = __expf(lo[j] - mx); se += ex[j]; }
#pragma unroll
    for (int j = 0; j < 3; ++j) out[j] = ex[j] / se;
}

extern "C" void kernel_launch(void* const* d_in, const int* in_sizes, int n_in,
                              void* d_out, int out_size, void* d_ws, size_t ws_size,
                              hipStream_t stream) {
    const float* x    = (const float*)d_in[0];
    const float* W1   = (const float*)d_in[1];
    const float* as1w = (const float*)d_in[2];
    const float* ad1w = (const float*)d_in[3];
    const float* b1   = (const float*)d_in[4];
    const float* W2   = (const float*)d_in[5];
    const float* as2w = (const float*)d_in[6];
    const float* ad2w = (const float*)d_in[7];
    const float* b2w  = (const float*)d_in[8];
    const float* linW = (const float*)d_in[9];
    const float* linb = (const float*)d_in[10];
    const int*   ei   = (const int*)d_in[11];

    const int N = in_sizes[0] / 64;       // 50000
    const int E = in_sizes[11] / 2;       // 800000

    float* ws = (float*)d_ws;
    __half* h1h  = (__half*)ws;                          // N*128 halves
    float*  hact = ws + (size_t)N * 64;                  // N*128 fp32
    float* asrc1 = hact + (size_t)N * 128;               // N*4
    float* adst1 = asrc1 + (size_t)N * 4;                // N*4
    float* asrc2 = adst1 + (size_t)N * 4;                // N
    float* adst2 = asrc2 + (size_t)N;                    // N
    float* gsum  = adst2 + (size_t)N;                    // 32
    // layer-2 aliases inside h1h region (dead after pull_agg1):
    __half* h2h  = (__half*)ws;                          // N*32 halves
    float*  out2 = ws + (size_t)N * 16;                  // N*32 fp32
    // int region: deg + slot-col
    int* deg     = (int*)(gsum + 32);        // N
    int* col     = deg + N;                  // N*CAP

    auto cdiv = [](int a, int b) { return (a + b - 1) / b; };

    hipMemsetAsync(deg, 0, (size_t)N * sizeof(int), stream);
    hipMemsetAsync(gsum, 0, 32 * sizeof(float), stream);

    // ---- XCD-sliced slot-CSR build ----
    scatter_k<<<SCB, 256, 0, stream>>>(ei, deg, col, E, N);

    // ---- layer 1 ----
    gemm1_k<<<cdiv(N, 32), 256, 0, stream>>>(x, W1, as1w, ad1w, h1h, asrc1, adst1, N);
    pull_agg1_k<<<cdiv(N, 4), 256, 0, stream>>>(deg, col, asrc1, adst1, h1h, b1, hact, N);

    // ---- layer 2 ----
    gemm2_k<<<cdiv(N, 128), 256, 0, stream>>>(hact, W2, as2w, ad2w, h2h, asrc2, adst2, N);
    pull_agg2_k<<<cdiv(N, 8), 256, 0, stream>>>(deg, col, asrc2, adst2, h2h, out2, N);

    // ---- readout ----
    colmean_k<<<256, 256, 0, stream>>>(out2, gsum, N);
    final_k<<<1, 64, 0, stream>>>(gsum, b2w, linW, linb, (float*)d_out, N);
}